// Round 1
// baseline (1840.293 us; speedup 1.0000x reference)
//
#include <hip/hip_runtime.h>
#include <cstdint>

#define S_LEN 2048
#define D_K   64
#define M_Q   32      // query rows per workgroup
#define SSTR  2056    // sS row stride (bf16 elems): 16B-aligned rows + bank spread
#define QSTR  72
#define CSTR  68
#define LOG2E 1.44269504088896340736f

typedef __attribute__((ext_vector_type(8))) short short8;  // 8 x bf16 (4 VGPRs)
typedef __attribute__((ext_vector_type(4))) float f4;

__device__ __forceinline__ short f2b(float f) {   // fp32 -> bf16 (RNE)
    union { float f; uint32_t u; } x; x.f = f;
    uint32_t r = x.u + 0x7FFFu + ((x.u >> 16) & 1u);
    return (short)(r >> 16);
}
__device__ __forceinline__ float b2f(short b) {
    union { uint32_t u; float f; } x;
    x.u = ((uint32_t)(uint16_t)b) << 16;
    return x.f;
}

__global__ __launch_bounds__(256, 1) void attn_fused(
    const float* __restrict__ qg, const float* __restrict__ kg,
    const float* __restrict__ vg, const int* __restrict__ mg,
    float* __restrict__ ctxg, float* __restrict__ attng)
{
    __shared__ short sS[M_Q * SSTR];   // 131,584 B : scores then probabilities (bf16)
    __shared__ short sQ[M_Q * QSTR];   //   4,608 B : Q tile (bf16)
    __shared__ float sCtx[M_Q * CSTR]; //   8,704 B : PV cross-wave reduction

    const int tid  = threadIdx.x;
    const int wave = tid >> 6;
    const int lane = tid & 63;
    const int quad = lane >> 4;
    const int l16  = lane & 15;

    const int bh = blockIdx.x >> 6;   // (b*H + h), 0..63
    const int qt = blockIdx.x & 63;   // query tile, fast index -> same-head blocks adjacent (L2)
    const int bb = bh >> 4;           // batch index

    const float* qp = qg + (size_t)bh * S_LEN * D_K + (size_t)qt * M_Q * D_K;
    const float* kp = kg + (size_t)bh * D_K * S_LEN;           // K is [d][t]
    const float* vp = vg + (size_t)bh * S_LEN * D_K;
    const int*   mp = mg + (size_t)bb * S_LEN;
    float* cp = ctxg + (size_t)bh * S_LEN * D_K + (size_t)qt * M_Q * D_K;
    float* ap = attng + ((size_t)bh * S_LEN + (size_t)qt * M_Q) * S_LEN;

    // ---- stage Q tile into LDS as bf16 ----
    {
        const int r = tid >> 3;
        const int c = (tid & 7) * 8;
        f4 a0 = *(const f4*)(qp + r * D_K + c);
        f4 a1 = *(const f4*)(qp + r * D_K + c + 4);
        short8 s8;
        #pragma unroll
        for (int j = 0; j < 4; ++j) { s8[j] = f2b(a0[j]); s8[4 + j] = f2b(a1[j]); }
        *(short8*)(&sQ[r * QSTR + c]) = s8;
    }
    __syncthreads();

    // A-operand frags for QK^T: A[m=l16][k=quad*8+j], two k-halves, two 16-row tiles
    short8 aq[2][2];
    #pragma unroll
    for (int rb = 0; rb < 2; ++rb)
        #pragma unroll
        for (int h = 0; h < 2; ++h)
            aq[rb][h] = *(const short8*)(&sQ[(rb * 16 + l16) * QSTR + h * 32 + quad * 8]);

    // ---- phase 1: scores = scale*Q.K, mask, -> sS (bf16, C-layout scatter) ----
    for (int cblk = 0; cblk < 32; ++cblk) {
        const int t  = (wave * 32 + cblk) * 16 + l16;
        const int mk = mp[t];
        short8 blo, bhi;  // B[k=d][n=t]: lane holds column t, 8 consecutive d per quad
        #pragma unroll
        for (int j = 0; j < 8; ++j) {
            blo[j] = f2b(kp[(size_t)(quad * 8 + j) * S_LEN + t]);
            bhi[j] = f2b(kp[(size_t)(32 + quad * 8 + j) * S_LEN + t]);
        }
        #pragma unroll
        for (int rb = 0; rb < 2; ++rb) {
            f4 acc = {0.f, 0.f, 0.f, 0.f};
            acc = __builtin_amdgcn_mfma_f32_16x16x32_bf16(aq[rb][0], blo, acc, 0, 0, 0);
            acc = __builtin_amdgcn_mfma_f32_16x16x32_bf16(aq[rb][1], bhi, acc, 0, 0, 0);
            #pragma unroll
            for (int rr = 0; rr < 4; ++rr) {
                const int row = rb * 16 + quad * 4 + rr;   // C/D: row=(lane>>4)*4+reg
                const float val = mk ? -1e9f : acc[rr] * 0.125f;
                sS[row * SSTR + t] = f2b(val);
            }
        }
    }
    __syncthreads();

    // ---- phase 2: row softmax; write fp32 attn (nontemporal) + bf16 p back to sS ----
    {
        const int r = tid >> 3;   // row 0..31, 8 threads per row (same wave)
        const int i = tid & 7;
        short* srow = &sS[r * SSTR];
        float mx = -3.0e38f;
        for (int kk = 0; kk < 32; ++kk) {
            short8 x = *(const short8*)(srow + 8 * i + 64 * kk);
            #pragma unroll
            for (int j = 0; j < 8; ++j) mx = fmaxf(mx, b2f(x[j]));
        }
        mx = fmaxf(mx, __shfl_xor(mx, 1));
        mx = fmaxf(mx, __shfl_xor(mx, 2));
        mx = fmaxf(mx, __shfl_xor(mx, 4));
        float sum = 0.f;
        for (int kk = 0; kk < 32; ++kk) {
            short8 x = *(const short8*)(srow + 8 * i + 64 * kk);
            #pragma unroll
            for (int j = 0; j < 8; ++j)
                sum += __builtin_amdgcn_exp2f((b2f(x[j]) - mx) * LOG2E);
        }
        sum += __shfl_xor(sum, 1);
        sum += __shfl_xor(sum, 2);
        sum += __shfl_xor(sum, 4);
        const float inv = 1.0f / sum;
        float* arow = ap + (size_t)r * S_LEN;
        for (int kk = 0; kk < 32; ++kk) {
            const int c0 = 8 * i + 64 * kk;
            short8 x = *(const short8*)(srow + c0);
            short8 pb;
            f4 o0, o1;
            #pragma unroll
            for (int j = 0; j < 8; ++j) {
                const float e = __builtin_amdgcn_exp2f((b2f(x[j]) - mx) * LOG2E) * inv;
                pb[j] = f2b(e);
                if (j < 4) o0[j] = e; else o1[j - 4] = e;
            }
            *(short8*)(srow + c0) = pb;                        // p (bf16) for PV
            __builtin_nontemporal_store(o0, (f4*)(arow + c0));     // streaming 1 GB
            __builtin_nontemporal_store(o1, (f4*)(arow + c0 + 4));
        }
    }
    __syncthreads();

    // ---- phase 3: context = P.V ; K-split across waves (512 keys each) ----
    f4 acc[2][4];
    #pragma unroll
    for (int rb = 0; rb < 2; ++rb)
        #pragma unroll
        for (int db = 0; db < 4; ++db)
            acc[rb][db] = (f4){0.f, 0.f, 0.f, 0.f};

    for (int ks = 0; ks < 16; ++ks) {
        const int t0 = wave * 512 + ks * 32;
        // A frags: p rows straight out of sS (b128, conflict-free)
        short8 a0 = *(const short8*)(&sS[l16 * SSTR + t0 + quad * 8]);
        short8 a1 = *(const short8*)(&sS[(16 + l16) * SSTR + t0 + quad * 8]);
        #pragma unroll
        for (int db = 0; db < 4; ++db) {
            short8 bv;  // B[k=t][n=d]: lane holds V column d, 8 consecutive t per quad
            #pragma unroll
            for (int j = 0; j < 8; ++j)
                bv[j] = f2b(vp[(size_t)(t0 + quad * 8 + j) * D_K + db * 16 + l16]);
            acc[0][db] = __builtin_amdgcn_mfma_f32_16x16x32_bf16(a0, bv, acc[0][db], 0, 0, 0);
            acc[1][db] = __builtin_amdgcn_mfma_f32_16x16x32_bf16(a1, bv, acc[1][db], 0, 0, 0);
        }
    }

    // cross-wave reduction of partial contexts
    for (int w2 = 0; w2 < 4; ++w2) {
        if (wave == w2) {
            #pragma unroll
            for (int rb = 0; rb < 2; ++rb)
                #pragma unroll
                for (int db = 0; db < 4; ++db)
                    #pragma unroll
                    for (int rr = 0; rr < 4; ++rr) {
                        const int row = rb * 16 + quad * 4 + rr;
                        const int col = db * 16 + l16;
                        if (w2 == 0) sCtx[row * CSTR + col]  = acc[rb][db][rr];
                        else         sCtx[row * CSTR + col] += acc[rb][db][rr];
                    }
        }
        __syncthreads();
    }

    {
        const int r = tid >> 3;
        const int i = tid & 7;
        f4 o0 = *(const f4*)(&sCtx[r * CSTR + 8 * i]);
        f4 o1 = *(const f4*)(&sCtx[r * CSTR + 8 * i + 4]);
        *(f4*)(cp + (size_t)r * D_K + 8 * i)     = o0;
        *(f4*)(cp + (size_t)r * D_K + 8 * i + 4) = o1;
    }
}

extern "C" void kernel_launch(void* const* d_in, const int* in_sizes, int n_in,
                              void* d_out, int out_size, void* d_ws, size_t ws_size,
                              hipStream_t stream) {
    const float* q = (const float*)d_in[0];
    const float* k = (const float*)d_in[1];
    const float* v = (const float*)d_in[2];
    const int* mask = (const int*)d_in[3];   // jnp.bool_ -> int32 per harness convention
    float* out = (float*)d_out;
    float* ctx  = out;                                     // (4,16,2048,64)
    float* attn = out + (size_t)4 * 16 * 2048 * 64;        // (4,16,2048,2048)
    attn_fused<<<dim3(4096), dim3(256), 0, stream>>>(q, k, v, mask, ctx, attn);
}